// Round 7
// baseline (11917.271 us; speedup 1.0000x reference)
//
#include <hip/hip_runtime.h>

#define Tt  128
#define HID 512

// DPP quad-perm helper: cross-lane xor-1 / xor-2 on the VALU pipe (no DS op).
#define DPP_QP(x, CTRL) \
    __int_as_float(__builtin_amdgcn_update_dpp( \
        __float_as_int(x), __float_as_int(x), (CTRL), 0xF, 0xF, false))
#define DPP_XOR1(x) DPP_QP(x, 0xB1)   // quad_perm [1,0,3,2]
#define DPP_XOR2(x) DPP_QP(x, 0x4E)   // quad_perm [2,3,0,1]

// Generic C[m,n] = sum_k A[m,k]*Bw[r(n),k] (+bias[r(n)]) (+C0[m/c0div, n])
// nperm: physical col n <-> logical weight row r(n) = (n&3)*512 + (n>>2),
// i.e. output stored gate-interleaved [.., j, 4gates] while writes stay coalesced.
__global__ __launch_bounds__(256)
void gemm_bt(const float* __restrict__ A, const float* __restrict__ Bw,
             const float* __restrict__ bias, const float* __restrict__ C0,
             float* __restrict__ C,
             int M, int N, int K, int lda, int ldb, int ldc, int ldc0,
             int c0div, int nperm)
{
    __shared__ float As[16][68];
    __shared__ float Bs[16][68];
    const int n0 = blockIdx.x * 64;
    const int m0 = blockIdx.y * 64;
    const int tid = threadIdx.x;
    const int tx = tid & 15, ty = tid >> 4;
    float acc[4][4];
#pragma unroll
    for (int i = 0; i < 4; i++)
#pragma unroll
        for (int j = 0; j < 4; j++) acc[i][j] = 0.f;

    for (int k0 = 0; k0 < K; k0 += 16) {
#pragma unroll
        for (int i = 0; i < 4; i++) {
            int e = tid + i * 256;
            int m = e >> 4, k = e & 15;
            As[k][m] = A[(size_t)(m0 + m) * lda + (k0 + k)];
        }
#pragma unroll
        for (int i = 0; i < 4; i++) {
            int e = tid + i * 256;
            int n = e >> 4, k = e & 15;
            int gn = n0 + n;
            int gr = nperm ? ((gn & 3) * HID + (gn >> 2)) : gn;
            Bs[k][n] = (gn < N) ? Bw[(size_t)gr * ldb + (k0 + k)] : 0.f;
        }
        __syncthreads();
#pragma unroll
        for (int kk = 0; kk < 16; kk++) {
            float4 av = *(const float4*)&As[kk][ty * 4];
            float4 bv = *(const float4*)&Bs[kk][tx * 4];
            float a[4] = {av.x, av.y, av.z, av.w};
            float b[4] = {bv.x, bv.y, bv.z, bv.w};
#pragma unroll
            for (int i = 0; i < 4; i++)
#pragma unroll
                for (int j = 0; j < 4; j++)
                    acc[i][j] += a[i] * b[j];
        }
        __syncthreads();
    }
#pragma unroll
    for (int i = 0; i < 4; i++) {
        int m = m0 + ty * 4 + i;
        const float* c0row = C0 ? (C0 + (size_t)(m / c0div) * ldc0) : nullptr;
#pragma unroll
        for (int j = 0; j < 4; j++) {
            int n = n0 + tx * 4 + j;
            if (n < N) {
                float v = acc[i][j];
                if (bias)  v += bias[nperm ? ((n & 3) * HID + (n >> 2)) : n];
                if (c0row) v += c0row[n];
                C[(size_t)m * ldc + n] = v;
            }
        }
    }
}

// Weight-stationary persistent LSTM recurrence, SIZED FOR THE 128-VGPR CAP.
// (r2-r6 lesson: this toolchain pins this kernel's VGPR budget at 128
// regardless of launch_bounds / waves_per_eu / LDS padding; ~150+ live regs
// spill-cycled 6.7 GB of scratch HBM traffic. So: fit in 128.)
//
// 256 blocks x 1024 threads (16 waves, 1 block/CU via 96 KB LDS pad).
// bt = blockIdx&7 (32 b rows), jt = blockIdx>>3 (16 j cols, 4 gates = 64 W
// rows/block). Wave w [0,16) owns j = j0+w. Lane: bit5 = rh (gate pair),
// bits0-4 = kc (16-float k chunk), bit4 doubles as a task-duplicate bit.
// Thread W slice: 2 rows (gates 2rh+gg) x 16 k = 32 VGPR, loaded once.
// Per step: MAC over 32 b in 4 groups of 8 (P[16] = 8b x 2gg), then a 4-step
// reduce-scatter over lane bits 1,2,4,8 (masks 1,2 on DPP/VALU pipe) plus a
// mask-16 allreduce (bit4 not consumed -> 2x dup). Each lane ends with gate
// (2rh+gg_p) of b = gb*8+i_p. After 4 gb groups: 4x4 lane transpose across
// bits {32 (rh), 8 (gg_p)} (same verified dataflow as r3, mask 16->8) gives
// every lane gates 0..3 of b = b0+(2rh+gg_p)*8+i_p, j = j0+w. Dup lanes
// (bit4) split the two stores: dup=0 writes the h exchange buf, dup=1 writes
// hiddens. Register budget: 32 Wr + 16 P + 4 Xv + 16 stage + ~40 misc ~ 110.
//
// h exchange via the transposed global layout (float4 idx b*128+kk4*32+kc),
// staged LDS<-global by straight register copy (conflict-free b128 reads).
// Sync: per-bt flag counters (agent-scope release/acquire), 3 barriers/step.
__global__ __launch_bounds__(1024)
void lstm_seq(const float* __restrict__ gin, const float* __restrict__ Whh,
              float* __restrict__ hA, float* __restrict__ hB,
              float* __restrict__ hiddens, unsigned int* __restrict__ flags)
{
    __shared__ float4 Hs[6144];        // 96 KB total; [0,4096) used:
                                       // [b_local 0..31][kk4 0..3][kc 0..31]
    const int tid = threadIdx.x;
    const int l   = tid & 63;
    const int w   = tid >> 6;          // 0..15 -> j (wave index)
    const int bt  = blockIdx.x & 7;
    const int jt  = blockIdx.x >> 3;   // 0..31
    const int b0  = bt * 32;
    const int j0  = jt * 16;
    const int rh  = l >> 5;            // gate-pair bit
    const int kc  = l & 31;            // k chunk [kc*16, kc*16+16)

    // one-time W_hh load: 2 rows x 4 float4 = 32 VGPR. gate = rh*2+gg, col j0+w
    float4 Wr[2][4];
#pragma unroll
    for (int gg = 0; gg < 2; ++gg) {
        const float4* src = (const float4*)Whh +
            (size_t)((rh * 2 + gg) * HID + j0 + w) * 128 + kc * 4;
#pragma unroll
        for (int q2 = 0; q2 < 4; ++q2) Wr[gg][q2] = src[q2];
    }

    // pointwise task decode (RS consumes: mask1<->i2, mask2<->i1, mask4<->i0,
    // mask8<->gg; mask16 = allreduce -> bit4 is a pure duplicate)
    const int i_p  = ((kc & 1) << 2) | (kc & 2) | ((kc >> 2) & 1);
    const int gg_p = (kc >> 3) & 1;
    const int dup  = (kc >> 4) & 1;
    const int bp = b0 + (rh * 2 + gg_p) * 8 + i_p;   // global b of this lane's task
    const int jp = j0 + w;                           // global j
    // transposed h position (float index) for (bp, jp): k == jp
    const size_t hpos = ((size_t)bp * 128 + ((jp >> 2) & 3) * 32 + (jp >> 4)) * 4 + (jp & 3);

    float cr = 0.f;

    for (int t = 0; t < Tt; ++t) {
        // prefetch the 4 gate inputs (gin is gate-interleaved [b][t][j][4])
        float4 gv = *(const float4*)(gin + ((size_t)bp * Tt + t) * 2048 + jp * 4);

        float Xv0 = 0.f, Xv1 = 0.f, Xv2 = 0.f, Xv3 = 0.f;
        if (t > 0) {
            if (tid == 0) {
                while (__hip_atomic_load(&flags[bt], __ATOMIC_ACQUIRE,
                                         __HIP_MEMORY_SCOPE_AGENT) < 32u * (unsigned)t)
                    __builtin_amdgcn_s_sleep(1);
            }
            __syncthreads();
            // stage 32 b x 512 h (64 KB) -> LDS: straight register-staged copy
            {
                const float4* hin4 =
                    (const float4*)(((t - 1) & 1) ? hB : hA) + (size_t)b0 * 128;
                float4 tmp[4];
#pragma unroll
                for (int q2 = 0; q2 < 4; ++q2)
                    tmp[q2] = hin4[(q2 * 16 + w) * 64 + l];
#pragma unroll
                for (int q2 = 0; q2 < 4; ++q2)
                    Hs[(q2 * 16 + w) * 64 + l] = tmp[q2];
            }
            __syncthreads();

#pragma unroll
            for (int gb = 0; gb < 4; ++gb) {       // 4 b-groups of 8
                float P[16];                       // [i 0..7][gg 0..1]
#pragma unroll
                for (int v = 0; v < 16; ++v) P[v] = 0.f;
#pragma unroll
                for (int i = 0; i < 8; ++i) {
                    const float4* hp = &Hs[(gb * 8 + i) * 128 + kc];
                    float4 h0 = hp[0], h1 = hp[32], h2 = hp[64], h3 = hp[96];
#pragma unroll
                    for (int gg = 0; gg < 2; ++gg) {
                        P[i * 2 + gg] +=
                            Wr[gg][0].x * h0.x + Wr[gg][0].y * h0.y + Wr[gg][0].z * h0.z + Wr[gg][0].w * h0.w +
                            Wr[gg][1].x * h1.x + Wr[gg][1].y * h1.y + Wr[gg][1].z * h1.z + Wr[gg][1].w * h1.w +
                            Wr[gg][2].x * h2.x + Wr[gg][2].y * h2.y + Wr[gg][2].z * h2.z + Wr[gg][2].w * h2.w +
                            Wr[gg][3].x * h3.x + Wr[gg][3].y * h3.y + Wr[gg][3].z * h3.z + Wr[gg][3].w * h3.w;
                    }
                }
                // reduce-scatter 16 values over lane bits 1,2,4,8; hi keeps
                // top half (lane-bit == value-bit after each step).
                {   // step 1: mask 1 (DPP, VALU pipe), 8 sends  (v3 = i2)
                    const bool hi = (l & 1) != 0;
#pragma unroll
                    for (int x = 0; x < 8; ++x) {
                        float a = P[x], b2 = P[8 + x];
                        float keep = hi ? b2 : a;
                        float send = hi ? a : b2;
                        P[x] = keep + DPP_XOR1(send);
                    }
                }
                {   // step 2: mask 2 (DPP), 4 sends            (v2 = i1)
                    const bool hi = (l & 2) != 0;
#pragma unroll
                    for (int x = 0; x < 4; ++x) {
                        float a = P[x], b2 = P[4 + x];
                        float keep = hi ? b2 : a;
                        float send = hi ? a : b2;
                        P[x] = keep + DPP_XOR2(send);
                    }
                }
                {   // step 3: mask 4, 2 sends                  (v1 = i0)
                    const bool hi = (l & 4) != 0;
#pragma unroll
                    for (int x = 0; x < 2; ++x) {
                        float a = P[x], b2 = P[2 + x];
                        float keep = hi ? b2 : a;
                        float send = hi ? a : b2;
                        P[x] = keep + __shfl_xor(send, 4, 64);
                    }
                }
                {   // step 4: mask 8, 1 send                   (v0 = gg)
                    const bool hi = (l & 8) != 0;
                    float a = P[0], b2 = P[1];
                    float keep = hi ? b2 : a;
                    float send = hi ? a : b2;
                    P[0] = keep + __shfl_xor(send, 8, 64);
                }
                // step 5: mask 16 allreduce (bit4 not a value bit -> dup)
                P[0] += __shfl_xor(P[0], 16, 64);

                if      (gb == 0) Xv0 = P[0];
                else if (gb == 1) Xv1 = P[0];
                else if (gb == 2) Xv2 = P[0];
                else              Xv3 = P[0];
            }
        }
        // 4x4 lane transpose across bits {5 (rh), 3 (gg_p)}: trade gate bits
        // for b-group bits so each lane gets all 4 gates of its (bp, jp).
        {
            const bool qb = rh != 0, pb = gg_p != 0;
            float rA = __shfl_xor(qb ? Xv0 : Xv2, 32, 64);
            float rB = __shfl_xor(qb ? Xv1 : Xv3, 32, 64);
            float U0 = qb ? rA : Xv0, U1 = qb ? rB : Xv1;
            float U2 = qb ? Xv2 : rA, U3 = qb ? Xv3 : rB;
            float sA = __shfl_xor(pb ? U0 : U1, 8, 64);
            float sB = __shfl_xor(pb ? U2 : U3, 8, 64);
            float Y0 = pb ? sA : U0, Y1 = pb ? U1 : sA;
            float Y2 = pb ? sB : U2, Y3 = pb ? U3 : sB;

            float gi = Y0 + gv.x;
            float gf = Y1 + gv.y;
            float gc = Y2 + gv.z;
            float go = Y3 + gv.w;

            float si = 1.f / (1.f + __expf(-gi));
            float sf = 1.f / (1.f + __expf(-gf));
            float so = 1.f / (1.f + __expf(-go));
            float tg = 1.f - 2.f / (1.f + __expf(2.f * gc));
            float cv = sf * cr + si * tg;
            cr = cv;
            float th = 1.f - 2.f / (1.f + __expf(2.f * cv));
            float hv = so * th;

            // dup lanes split the two stores (identical values either way)
            if (dup == 0) {
                float* hw = (t & 1) ? hB : hA;
                hw[hpos] = hv;                                    // exchange buf
            } else {
                hiddens[((size_t)bp * Tt + t) * HID + jp] = hv;   // for GEMM 7
            }
        }
        __syncthreads();   // all waves drain reads+stores (vmcnt0 at barrier)
        if (tid == 0) {
            __threadfence();
            __hip_atomic_fetch_add(&flags[bt], 1u, __ATOMIC_RELEASE,
                                   __HIP_MEMORY_SCOPE_AGENT);
        }
    }
}

extern "C" void kernel_launch(void* const* d_in, const int* in_sizes, int n_in,
                              void* d_out, int out_size, void* d_ws, size_t ws_size,
                              hipStream_t stream)
{
    const float* images = (const float*)d_in[0];
    const float* caps   = (const float*)d_in[1];
    const float* W_fc   = (const float*)d_in[2];
    const float* b_fc   = (const float*)d_in[3];
    const float* W_att  = (const float*)d_in[4];
    const float* b_att  = (const float*)d_in[5];
    const float* W_ih   = (const float*)d_in[6];
    const float* b_ih   = (const float*)d_in[7];
    const float* W_hh   = (const float*)d_in[8];
    const float* b_hh   = (const float*)d_in[9];
    const float* W_out  = (const float*)d_in[10];
    const float* b_out  = (const float*)d_in[11];
    float* out = (float*)d_out;

    float* ws       = (float*)d_ws;
    float* feats    = ws;                  // 256*256
    float* att_base = feats + 65536;       // 256*256
    float* gin_base = att_base + 65536;    // 256*2048 (gate-interleaved)
    float* hA       = gin_base + 524288;   // 256*512 (transposed layout)
    float* hB       = hA + 131072;
    float* ctx_all  = hB + 131072;         // 32768*256
    float* hiddens  = ctx_all + 8388608;   // 32768*512
    float* gin_all  = hiddens + 16777216;  // 32768*2048 (gate-interleaved)
    unsigned int* flags = (unsigned int*)(gin_all + 67108864);  // 8 counters

    hipMemsetAsync(flags, 0, 8 * sizeof(unsigned int), stream);

    // 1. feats = images @ W_fc^T + b_fc            [256,256]
    gemm_bt<<<dim3(4, 4), 256, 0, stream>>>(images, W_fc, b_fc, nullptr, feats,
        256, 256, 2048, 2048, 2048, 256, 0, 1, 0);
    // 2. att_base = feats @ W_att[:, :256]^T + b_att   [256,256]
    gemm_bt<<<dim3(4, 4), 256, 0, stream>>>(feats, W_att, b_att, nullptr, att_base,
        256, 256, 256, 256, 768, 256, 0, 1, 0);
    // 3. gin_base = feats @ W_ih[:, :256]^T + b_ih     [256,2048] gate-interleaved
    gemm_bt<<<dim3(32, 4), 256, 0, stream>>>(feats, W_ih, b_ih, nullptr, gin_base,
        256, 2048, 256, 256, 512, 2048, 0, 1, 1);
    // 4. ctx_all = caps @ W_att[:, 256:]^T + att_base  [32768,256]
    gemm_bt<<<dim3(4, 512), 256, 0, stream>>>(caps, W_att + 256, nullptr, att_base, ctx_all,
        32768, 256, 512, 512, 768, 256, 256, Tt, 0);
    // 5. gin_all = ctx_all @ W_ih[:, 256:]^T + gin_base + b_hh   [32768,2048] interleaved
    gemm_bt<<<dim3(32, 512), 256, 0, stream>>>(ctx_all, W_ih + 256, b_hh, gin_base, gin_all,
        32768, 2048, 256, 256, 512, 2048, 2048, Tt, 1);

    // 6. recurrence: weight-stationary persistent kernel, 256 x 1024, flag-synced
    {
        void* args[] = { (void*)&gin_all, (void*)&W_hh, (void*)&hA, (void*)&hB,
                         (void*)&hiddens, (void*)&flags };
        hipLaunchCooperativeKernel((void*)lstm_seq, dim3(256), dim3(1024),
                                   args, 0, stream);
    }

    // 7. out = hiddens @ W_out^T + b_out   [32768,1004]
    gemm_bt<<<dim3(16, 512), 256, 0, stream>>>(hiddens, W_out, b_out, nullptr, out,
        32768, 1004, 512, 512, 512, 1004, 0, 1, 0);
}

// Round 8
// 7315.425 us; speedup vs baseline: 1.6291x; 1.6291x over previous
//
#include <hip/hip_runtime.h>

#define Tt  128
#define HID 512

// DPP quad-perm helper: cross-lane xor-1 / xor-2 on the VALU pipe (no DS op).
#define DPP_QP(x, CTRL) \
    __int_as_float(__builtin_amdgcn_update_dpp( \
        __float_as_int(x), __float_as_int(x), (CTRL), 0xF, 0xF, false))
#define DPP_XOR1(x) DPP_QP(x, 0xB1)   // quad_perm [1,0,3,2]
#define DPP_XOR2(x) DPP_QP(x, 0x4E)   // quad_perm [2,3,0,1]

// Generic C[m,n] = sum_k A[m,k]*Bw[r(n),k] (+bias[r(n)]) (+C0[m/c0div, n])
// nperm: physical col n <-> logical weight row r(n) = (n&3)*512 + (n>>2),
// i.e. output stored gate-interleaved [.., j, 4gates] while writes stay coalesced.
__global__ __launch_bounds__(256)
void gemm_bt(const float* __restrict__ A, const float* __restrict__ Bw,
             const float* __restrict__ bias, const float* __restrict__ C0,
             float* __restrict__ C,
             int M, int N, int K, int lda, int ldb, int ldc, int ldc0,
             int c0div, int nperm)
{
    __shared__ float As[16][68];
    __shared__ float Bs[16][68];
    const int n0 = blockIdx.x * 64;
    const int m0 = blockIdx.y * 64;
    const int tid = threadIdx.x;
    const int tx = tid & 15, ty = tid >> 4;
    float acc[4][4];
#pragma unroll
    for (int i = 0; i < 4; i++)
#pragma unroll
        for (int j = 0; j < 4; j++) acc[i][j] = 0.f;

    for (int k0 = 0; k0 < K; k0 += 16) {
#pragma unroll
        for (int i = 0; i < 4; i++) {
            int e = tid + i * 256;
            int m = e >> 4, k = e & 15;
            As[k][m] = A[(size_t)(m0 + m) * lda + (k0 + k)];
        }
#pragma unroll
        for (int i = 0; i < 4; i++) {
            int e = tid + i * 256;
            int n = e >> 4, k = e & 15;
            int gn = n0 + n;
            int gr = nperm ? ((gn & 3) * HID + (gn >> 2)) : gn;
            Bs[k][n] = (gn < N) ? Bw[(size_t)gr * ldb + (k0 + k)] : 0.f;
        }
        __syncthreads();
#pragma unroll
        for (int kk = 0; kk < 16; kk++) {
            float4 av = *(const float4*)&As[kk][ty * 4];
            float4 bv = *(const float4*)&Bs[kk][tx * 4];
            float a[4] = {av.x, av.y, av.z, av.w};
            float b[4] = {bv.x, bv.y, bv.z, bv.w};
#pragma unroll
            for (int i = 0; i < 4; i++)
#pragma unroll
                for (int j = 0; j < 4; j++)
                    acc[i][j] += a[i] * b[j];
        }
        __syncthreads();
    }
#pragma unroll
    for (int i = 0; i < 4; i++) {
        int m = m0 + ty * 4 + i;
        const float* c0row = C0 ? (C0 + (size_t)(m / c0div) * ldc0) : nullptr;
#pragma unroll
        for (int j = 0; j < 4; j++) {
            int n = n0 + tx * 4 + j;
            if (n < N) {
                float v = acc[i][j];
                if (bias)  v += bias[nperm ? ((n & 3) * HID + (n >> 2)) : n];
                if (c0row) v += c0row[n];
                C[(size_t)m * ldc + n] = v;
            }
        }
    }
}

// Weight-stationary persistent LSTM recurrence, spill-free layout.
// 256 blocks x 512 threads (8 waves, 1 block/CU). bt = blockIdx&7 (32 b),
// jt = blockIdx>>3 (16 j, 4 gates = 64 W rows/block). Lane: bit5 = rh (gate
// pair), bits0-4 = kc (16-float k chunk). Thread W slice: 4 rows (jj x gg,
// gate = rh*2+gg) x 16 k = 64 VGPR, loaded once. Per step: MAC over 32 b in
// 4 groups of 8 (P[32] = 8b x 4r), then 5-step reduce-scatter over the kc
// bits (masks 1,2 on the DPP/VALU pipe, 4/8/16 as DS shuffles). Each lane
// ends with 1 fully-summed value per group; a 2-stage 4x4 lane transpose
// (masks 32,16) gives every lane all 4 gates of one (b,j) -> all 512 lanes
// do the pointwise, c-state in 1 register.
//
// REGISTER BUDGET — the r2-r7 saga, resolved. Observed VGPR caps:
//   (512,2)->128, (512,-)->128, (1024,-)->64, (1024,4)->~64. One rule fits:
//   the 2nd launch_bounds arg acts as BLOCKS/CU (default 2); VGPR budget
//   = 512 / (blocks x block_waves / 4 SIMDs). waves_per_eu attrs and LDS
//   padding are IGNORED by this heuristic (r4/r6 falsified both).
//   The working set here is ~150-190 regs -> need cap 256 ->
//   __launch_bounds__(512, 1): 1 block/CU = 2 waves/EU = 256 VGPRs.
//   (The 96 KB LDS pad stays: hardware-enforces the same 1 block/CU.)
//
// h exchange via the transposed global layout (float4 idx b*128+kk4*32+kc),
// staged LDS<-global by straight register copy (conflict-free b128 reads).
// Sync: per-bt flag counters (agent-scope release/acquire), 3 barriers/step.
__global__ __launch_bounds__(512, 1)
void lstm_seq(const float* __restrict__ gin, const float* __restrict__ Whh,
              float* __restrict__ hA, float* __restrict__ hB,
              float* __restrict__ hiddens, unsigned int* __restrict__ flags)
{
    __shared__ float4 Hs[6144];        // 96 KB total; [0,4096) used:
                                       // [b_local 0..31][kk4 0..3][kc 0..31]
    const int tid = threadIdx.x;
    const int l   = tid & 63;
    const int w   = tid >> 6;          // 0..7 -> j pair group (wave index)
    const int bt  = blockIdx.x & 7;
    const int jt  = blockIdx.x >> 3;   // 0..31
    const int b0  = bt * 32;
    const int j0  = jt * 16;
    const int rh  = l >> 5;            // gate-pair bit
    const int kc  = l & 31;            // k chunk [kc*16, kc*16+16)

    // one-time W_hh load: 4 rows x 4 float4 = 64 VGPR. r = jj*2+gg, gate = rh*2+gg
    float4 Wr[4][4];
#pragma unroll
    for (int jj = 0; jj < 2; ++jj)
#pragma unroll
        for (int gg = 0; gg < 2; ++gg) {
            const float4* src = (const float4*)Whh +
                (size_t)((rh * 2 + gg) * HID + j0 + w * 2 + jj) * 128 + kc * 4;
#pragma unroll
            for (int q2 = 0; q2 < 4; ++q2) Wr[jj * 2 + gg][q2] = src[q2];
        }

    // pointwise task decode (from RS lane-bit consumption order):
    // step1 mask1<->i2, mask2<->i1, mask4<->i0, mask8<->jj, mask16<->gg
    const int i_p  = ((kc & 1) << 2) | (kc & 2) | ((kc >> 2) & 1);
    const int jj_p = (kc >> 3) & 1;
    const int gg_p = (kc >> 4) & 1;
    const int bp = b0 + (rh * 2 + gg_p) * 8 + i_p;   // global b of this lane's task
    const int jp = j0 + w * 2 + jj_p;                // global j
    // transposed h position (float index) for (bp, jp): k == jp
    const size_t hpos = ((size_t)bp * 128 + ((jp >> 2) & 3) * 32 + (jp >> 4)) * 4 + (jp & 3);

    float cr = 0.f;

    for (int t = 0; t < Tt; ++t) {
        // prefetch the 4 gate inputs (gin is gate-interleaved [b][t][j][4])
        float4 gv = *(const float4*)(gin + ((size_t)bp * Tt + t) * 2048 + jp * 4);

        float Xv0 = 0.f, Xv1 = 0.f, Xv2 = 0.f, Xv3 = 0.f;
        if (t > 0) {
            if (tid == 0) {
                while (__hip_atomic_load(&flags[bt], __ATOMIC_ACQUIRE,
                                         __HIP_MEMORY_SCOPE_AGENT) < 32u * (unsigned)t)
                    __builtin_amdgcn_s_sleep(1);
            }
            __syncthreads();
            // stage 32 b x 512 h (64 KB) -> LDS: straight register-staged copy
            {
                const float4* hin4 =
                    (const float4*)(((t - 1) & 1) ? hB : hA) + (size_t)b0 * 128;
                float4 tmp[8];
#pragma unroll
                for (int q2 = 0; q2 < 8; ++q2)
                    tmp[q2] = hin4[(q2 * 8 + w) * 64 + l];
#pragma unroll
                for (int q2 = 0; q2 < 8; ++q2)
                    Hs[(q2 * 8 + w) * 64 + l] = tmp[q2];
            }
            __syncthreads();

#pragma unroll
            for (int gb = 0; gb < 4; ++gb) {       // 4 b-groups of 8
                float P[32];                       // [i 0..7][r 0..3], r = jj*2+gg
#pragma unroll
                for (int v = 0; v < 32; ++v) P[v] = 0.f;
#pragma unroll
                for (int i = 0; i < 8; ++i) {
                    const float4* hp = &Hs[(gb * 8 + i) * 128 + kc];
                    float4 h0 = hp[0], h1 = hp[32], h2 = hp[64], h3 = hp[96];
#pragma unroll
                    for (int r = 0; r < 4; ++r) {
                        P[i * 4 + r] +=
                            Wr[r][0].x * h0.x + Wr[r][0].y * h0.y + Wr[r][0].z * h0.z + Wr[r][0].w * h0.w +
                            Wr[r][1].x * h1.x + Wr[r][1].y * h1.y + Wr[r][1].z * h1.z + Wr[r][1].w * h1.w +
                            Wr[r][2].x * h2.x + Wr[r][2].y * h2.y + Wr[r][2].z * h2.z + Wr[r][2].w * h2.w +
                            Wr[r][3].x * h3.x + Wr[r][3].y * h3.y + Wr[r][3].z * h3.z + Wr[r][3].w * h3.w;
                    }
                }
                // reduce-scatter 32 values -> 1 across the 5 kc lane bits.
                // hi lane keeps top half; after each step lane-bit == value-bit.
                {   // step 1: mask 1 (DPP, VALU pipe), 16 sends
                    const bool hi = (l & 1) != 0;
#pragma unroll
                    for (int x = 0; x < 16; ++x) {
                        float a = P[x], b2 = P[16 + x];
                        float keep = hi ? b2 : a;
                        float send = hi ? a : b2;
                        P[x] = keep + DPP_XOR1(send);
                    }
                }
                {   // step 2: mask 2 (DPP), 8 sends
                    const bool hi = (l & 2) != 0;
#pragma unroll
                    for (int x = 0; x < 8; ++x) {
                        float a = P[x], b2 = P[8 + x];
                        float keep = hi ? b2 : a;
                        float send = hi ? a : b2;
                        P[x] = keep + DPP_XOR2(send);
                    }
                }
                {   // step 3: mask 4 (ds swizzle), 4 sends
                    const bool hi = (l & 4) != 0;
#pragma unroll
                    for (int x = 0; x < 4; ++x) {
                        float a = P[x], b2 = P[4 + x];
                        float keep = hi ? b2 : a;
                        float send = hi ? a : b2;
                        P[x] = keep + __shfl_xor(send, 4, 64);
                    }
                }
                {   // step 4: mask 8, 2 sends
                    const bool hi = (l & 8) != 0;
#pragma unroll
                    for (int x = 0; x < 2; ++x) {
                        float a = P[x], b2 = P[2 + x];
                        float keep = hi ? b2 : a;
                        float send = hi ? a : b2;
                        P[x] = keep + __shfl_xor(send, 8, 64);
                    }
                }
                {   // step 5: mask 16, 1 send
                    const bool hi = (l & 16) != 0;
                    float a = P[0], b2 = P[1];
                    float keep = hi ? b2 : a;
                    float send = hi ? a : b2;
                    P[0] = keep + __shfl_xor(send, 16, 64);
                }
                if      (gb == 0) Xv0 = P[0];
                else if (gb == 1) Xv1 = P[0];
                else if (gb == 2) Xv2 = P[0];
                else              Xv3 = P[0];
            }
        }
        // 4x4 lane transpose across bits {5 (rh), 4 (gg)}: trade gate bits for
        // b-group bits so each lane gets all 4 gates of its (bp, jp).
        {
            const bool qb = rh != 0, pb = gg_p != 0;
            float rA = __shfl_xor(qb ? Xv0 : Xv2, 32, 64);
            float rB = __shfl_xor(qb ? Xv1 : Xv3, 32, 64);
            float U0 = qb ? rA : Xv0, U1 = qb ? rB : Xv1;
            float U2 = qb ? Xv2 : rA, U3 = qb ? Xv3 : rB;
            float sA = __shfl_xor(pb ? U0 : U1, 16, 64);
            float sB = __shfl_xor(pb ? U2 : U3, 16, 64);
            float Y0 = pb ? sA : U0, Y1 = pb ? U1 : sA;
            float Y2 = pb ? sB : U2, Y3 = pb ? U3 : sB;

            float gi = Y0 + gv.x;
            float gf = Y1 + gv.y;
            float gc = Y2 + gv.z;
            float go = Y3 + gv.w;

            float si = 1.f / (1.f + __expf(-gi));
            float sf = 1.f / (1.f + __expf(-gf));
            float so = 1.f / (1.f + __expf(-go));
            float tg = 1.f - 2.f / (1.f + __expf(2.f * gc));
            float cv = sf * cr + si * tg;
            cr = cv;
            float th = 1.f - 2.f / (1.f + __expf(2.f * cv));
            float hv = so * th;

            float* hw = (t & 1) ? hB : hA;
            hw[hpos] = hv;                                    // transposed exchange buf
            hiddens[((size_t)bp * Tt + t) * HID + jp] = hv;   // standard layout for GEMM
        }
        __syncthreads();   // all waves drain reads+stores (vmcnt0 at barrier)
        if (tid == 0) {
            __threadfence();
            __hip_atomic_fetch_add(&flags[bt], 1u, __ATOMIC_RELEASE,
                                   __HIP_MEMORY_SCOPE_AGENT);
        }
    }
}

extern "C" void kernel_launch(void* const* d_in, const int* in_sizes, int n_in,
                              void* d_out, int out_size, void* d_ws, size_t ws_size,
                              hipStream_t stream)
{
    const float* images = (const float*)d_in[0];
    const float* caps   = (const float*)d_in[1];
    const float* W_fc   = (const float*)d_in[2];
    const float* b_fc   = (const float*)d_in[3];
    const float* W_att  = (const float*)d_in[4];
    const float* b_att  = (const float*)d_in[5];
    const float* W_ih   = (const float*)d_in[6];
    const float* b_ih   = (const float*)d_in[7];
    const float* W_hh   = (const float*)d_in[8];
    const float* b_hh   = (const float*)d_in[9];
    const float* W_out  = (const float*)d_in[10];
    const float* b_out  = (const float*)d_in[11];
    float* out = (float*)d_out;

    float* ws       = (float*)d_ws;
    float* feats    = ws;                  // 256*256
    float* att_base = feats + 65536;       // 256*256
    float* gin_base = att_base + 65536;    // 256*2048 (gate-interleaved)
    float* hA       = gin_base + 524288;   // 256*512 (transposed layout)
    float* hB       = hA + 131072;
    float* ctx_all  = hB + 131072;         // 32768*256
    float* hiddens  = ctx_all + 8388608;   // 32768*512
    float* gin_all  = hiddens + 16777216;  // 32768*2048 (gate-interleaved)
    unsigned int* flags = (unsigned int*)(gin_all + 67108864);  // 8 counters

    hipMemsetAsync(flags, 0, 8 * sizeof(unsigned int), stream);

    // 1. feats = images @ W_fc^T + b_fc            [256,256]
    gemm_bt<<<dim3(4, 4), 256, 0, stream>>>(images, W_fc, b_fc, nullptr, feats,
        256, 256, 2048, 2048, 2048, 256, 0, 1, 0);
    // 2. att_base = feats @ W_att[:, :256]^T + b_att   [256,256]
    gemm_bt<<<dim3(4, 4), 256, 0, stream>>>(feats, W_att, b_att, nullptr, att_base,
        256, 256, 256, 256, 768, 256, 0, 1, 0);
    // 3. gin_base = feats @ W_ih[:, :256]^T + b_ih     [256,2048] gate-interleaved
    gemm_bt<<<dim3(32, 4), 256, 0, stream>>>(feats, W_ih, b_ih, nullptr, gin_base,
        256, 2048, 256, 256, 512, 2048, 0, 1, 1);
    // 4. ctx_all = caps @ W_att[:, 256:]^T + att_base  [32768,256]
    gemm_bt<<<dim3(4, 512), 256, 0, stream>>>(caps, W_att + 256, nullptr, att_base, ctx_all,
        32768, 256, 512, 512, 768, 256, 256, Tt, 0);
    // 5. gin_all = ctx_all @ W_ih[:, 256:]^T + gin_base + b_hh   [32768,2048] interleaved
    gemm_bt<<<dim3(32, 512), 256, 0, stream>>>(ctx_all, W_ih + 256, b_hh, gin_base, gin_all,
        32768, 2048, 256, 256, 512, 2048, 2048, Tt, 1);

    // 6. recurrence: weight-stationary persistent kernel, 256 x 512, flag-synced
    {
        void* args[] = { (void*)&gin_all, (void*)&W_hh, (void*)&hA, (void*)&hB,
                         (void*)&hiddens, (void*)&flags };
        hipLaunchCooperativeKernel((void*)lstm_seq, dim3(256), dim3(512),
                                   args, 0, stream);
    }

    // 7. out = hiddens @ W_out^T + b_out   [32768,1004]
    gemm_bt<<<dim3(16, 512), 256, 0, stream>>>(hiddens, W_out, b_out, nullptr, out,
        32768, 1004, 512, 512, 512, 1004, 0, 1, 0);
}

// Round 10
// 7007.388 us; speedup vs baseline: 1.7007x; 1.0440x over previous
//
#include <hip/hip_runtime.h>

#define Tt  128
#define HID 512

// DPP quad-perm helper: cross-lane xor-1 / xor-2 on the VALU pipe (no DS op).
#define DPP_QP(x, CTRL) \
    __int_as_float(__builtin_amdgcn_update_dpp( \
        __float_as_int(x), __float_as_int(x), (CTRL), 0xF, 0xF, false))
#define DPP_XOR1(x) DPP_QP(x, 0xB1)   // quad_perm [1,0,3,2]
#define DPP_XOR2(x) DPP_QP(x, 0x4E)   // quad_perm [2,3,0,1]

// Generic C[m,n] = sum_k A[m,k]*Bw[r(n),k] (+bias[r(n)]) (+C0[m/c0div, n])
// nperm: physical col n <-> logical weight row r(n) = (n&3)*512 + (n>>2),
// i.e. output stored gate-interleaved [.., j, 4gates] while writes stay coalesced.
__global__ __launch_bounds__(256)
void gemm_bt(const float* __restrict__ A, const float* __restrict__ Bw,
             const float* __restrict__ bias, const float* __restrict__ C0,
             float* __restrict__ C,
             int M, int N, int K, int lda, int ldb, int ldc, int ldc0,
             int c0div, int nperm)
{
    __shared__ float As[16][68];
    __shared__ float Bs[16][68];
    const int n0 = blockIdx.x * 64;
    const int m0 = blockIdx.y * 64;
    const int tid = threadIdx.x;
    const int tx = tid & 15, ty = tid >> 4;
    float acc[4][4];
#pragma unroll
    for (int i = 0; i < 4; i++)
#pragma unroll
        for (int j = 0; j < 4; j++) acc[i][j] = 0.f;

    for (int k0 = 0; k0 < K; k0 += 16) {
#pragma unroll
        for (int i = 0; i < 4; i++) {
            int e = tid + i * 256;
            int m = e >> 4, k = e & 15;
            As[k][m] = A[(size_t)(m0 + m) * lda + (k0 + k)];
        }
#pragma unroll
        for (int i = 0; i < 4; i++) {
            int e = tid + i * 256;
            int n = e >> 4, k = e & 15;
            int gn = n0 + n;
            int gr = nperm ? ((gn & 3) * HID + (gn >> 2)) : gn;
            Bs[k][n] = (gn < N) ? Bw[(size_t)gr * ldb + (k0 + k)] : 0.f;
        }
        __syncthreads();
#pragma unroll
        for (int kk = 0; kk < 16; kk++) {
            float4 av = *(const float4*)&As[kk][ty * 4];
            float4 bv = *(const float4*)&Bs[kk][tx * 4];
            float a[4] = {av.x, av.y, av.z, av.w};
            float b[4] = {bv.x, bv.y, bv.z, bv.w};
#pragma unroll
            for (int i = 0; i < 4; i++)
#pragma unroll
                for (int j = 0; j < 4; j++)
                    acc[i][j] += a[i] * b[j];
        }
        __syncthreads();
    }
#pragma unroll
    for (int i = 0; i < 4; i++) {
        int m = m0 + ty * 4 + i;
        const float* c0row = C0 ? (C0 + (size_t)(m / c0div) * ldc0) : nullptr;
#pragma unroll
        for (int j = 0; j < 4; j++) {
            int n = n0 + tx * 4 + j;
            if (n < N) {
                float v = acc[i][j];
                if (bias)  v += bias[nperm ? ((n & 3) * HID + (n >> 2)) : n];
                if (c0row) v += c0row[n];
                C[(size_t)m * ldc + n] = v;
            }
        }
    }
}

// Weight-stationary persistent LSTM recurrence — fits the observed 128-VGPR
// cap AND the proven 256-block / 1-block-per-CU cooperative geometry.
// (r2-r8: 512-thr blocks always get a 128-VGPR cap. r9's 512-block grid died
// in-container — 2-block/CU co-residency is unproven on this stack; every
// successful round ran 256 blocks. So: 256 blocks, bigger per-block tile.)
//
// 256 blocks x 512 threads (8 waves). bt = blockIdx&3 -> 4 pipelines of 64
// blocks, 64 b rows each (b0 = bt*64). jt = blockIdx>>2 in [0,64): 8 j cols
// x 4 gates = 32 W rows/block. Wave w in [0,8) owns j = j0+w. Lane: bit5 =
// rh (gate pair), bits0-4 = kc (16-float k chunk), bit4 also = dup bit.
// Thread W slice: 2 rows (gates 2rh+gg) x 16 k = 32 VGPR, loaded once
// (HW-verified math from r7). Per step: MAC over 64 b in 8 groups of 8
// (P[16] = 8b x 2gg), 4-step reduce-scatter over lane bits 1,2,4,8 (masks
// 1,2 on the DPP/VALU pipe) + mask-16 allreduce (bit4 unconsumed -> 2x dup).
// Lane ends with gate (2rh+gg_p) of b = gb*8+i_p for each of 8 gb. Two 4x4
// lane transposes across bits {32 (rh), 8 (gg_p)} (gb 0-3, then 4-7) give
// every lane all 4 gates of TWO tasks: (bp, jp) and (bp+32, jp); c-state =
// 2 registers. Dup lanes split the stores (dup=0 -> exchange buf, dup=1 ->
// hiddens). Peak live regs ~100 (32 W + 16 P + 32 staging tmp + misc).
//
// h exchange via the transposed global layout (float4 idx b*128+kk4*32+kc),
// staged LDS<-global by straight register copy, 128 KB (two 8-float4 rounds;
// 144 KB static LDS proven on this toolchain in r0; forces 1 block/CU).
// Sync: per-bt flag counters (target 64*t), agent-scope release/acquire,
// 3 barriers/step.
__global__ __launch_bounds__(512)
void lstm_seq(const float* __restrict__ gin, const float* __restrict__ Whh,
              float* __restrict__ hA, float* __restrict__ hB,
              float* __restrict__ hiddens, unsigned int* __restrict__ flags)
{
    __shared__ float4 Hs[8192];        // 128 KB: [b_local 0..63][kk4 0..3][kc 0..31]
    const int tid = threadIdx.x;
    const int l   = tid & 63;
    const int w   = tid >> 6;          // 0..7 -> j (wave index)
    const int bt  = blockIdx.x & 3;
    const int jt  = blockIdx.x >> 2;   // 0..63
    const int b0  = bt * 64;
    const int j0  = jt * 8;
    const int rh  = l >> 5;            // gate-pair bit
    const int kc  = l & 31;            // k chunk [kc*16, kc*16+16)

    // one-time W_hh load: 2 rows x 4 float4 = 32 VGPR. gate = rh*2+gg, col j0+w
    float4 Wr[2][4];
#pragma unroll
    for (int gg = 0; gg < 2; ++gg) {
        const float4* src = (const float4*)Whh +
            (size_t)((rh * 2 + gg) * HID + j0 + w) * 128 + kc * 4;
#pragma unroll
        for (int q2 = 0; q2 < 4; ++q2) Wr[gg][q2] = src[q2];
    }

    // pointwise task decode (RS consumes: mask1<->i2, mask2<->i1, mask4<->i0,
    // mask8<->gg; mask16 = allreduce -> bit4 is a pure duplicate)
    const int i_p  = ((kc & 1) << 2) | (kc & 2) | ((kc >> 2) & 1);
    const int gg_p = (kc >> 3) & 1;
    const int dup  = (kc >> 4) & 1;
    const int bp = b0 + (rh * 2 + gg_p) * 8 + i_p;   // task 1 b (task 2 = bp+32)
    const int jp = j0 + w;                           // global j
    // transposed h position (float index) for (bp, jp): k == jp
    const size_t hpos = ((size_t)bp * 128 + ((jp >> 2) & 3) * 32 + (jp >> 4)) * 4 + (jp & 3);

    float cr0 = 0.f, cr1 = 0.f;

    for (int t = 0; t < Tt; ++t) {
        // prefetch the 4 gate inputs for both tasks (gin is [b][t][j][4])
        float4 gvA = *(const float4*)(gin + ((size_t)bp * Tt + t) * 2048 + jp * 4);
        float4 gvB = *(const float4*)(gin + ((size_t)(bp + 32) * Tt + t) * 2048 + jp * 4);

        float Xv0 = 0.f, Xv1 = 0.f, Xv2 = 0.f, Xv3 = 0.f;
        float Xv4 = 0.f, Xv5 = 0.f, Xv6 = 0.f, Xv7 = 0.f;
        if (t > 0) {
            if (tid == 0) {
                while (__hip_atomic_load(&flags[bt], __ATOMIC_ACQUIRE,
                                         __HIP_MEMORY_SCOPE_AGENT) < 64u * (unsigned)t)
                    __builtin_amdgcn_s_sleep(1);
            }
            __syncthreads();
            // stage 64 b x 512 h (128 KB) -> LDS in two 8-float4 rounds
            {
                const float4* hin4 =
                    (const float4*)(((t - 1) & 1) ? hB : hA) + (size_t)b0 * 128;
                float4 tmp[8];
#pragma unroll
                for (int q2 = 0; q2 < 8; ++q2)
                    tmp[q2] = hin4[(q2 * 8 + w) * 64 + l];
#pragma unroll
                for (int q2 = 0; q2 < 8; ++q2)
                    Hs[(q2 * 8 + w) * 64 + l] = tmp[q2];
#pragma unroll
                for (int q2 = 0; q2 < 8; ++q2)
                    tmp[q2] = hin4[((q2 + 8) * 8 + w) * 64 + l];
#pragma unroll
                for (int q2 = 0; q2 < 8; ++q2)
                    Hs[((q2 + 8) * 8 + w) * 64 + l] = tmp[q2];
            }
            __syncthreads();

#pragma unroll
            for (int gb = 0; gb < 8; ++gb) {       // 8 b-groups of 8
                float P[16];                       // [i 0..7][gg 0..1]
#pragma unroll
                for (int v = 0; v < 16; ++v) P[v] = 0.f;
#pragma unroll
                for (int i = 0; i < 8; ++i) {
                    const float4* hp = &Hs[(gb * 8 + i) * 128 + kc];
                    float4 h0 = hp[0], h1 = hp[32], h2 = hp[64], h3 = hp[96];
#pragma unroll
                    for (int gg = 0; gg < 2; ++gg) {
                        P[i * 2 + gg] +=
                            Wr[gg][0].x * h0.x + Wr[gg][0].y * h0.y + Wr[gg][0].z * h0.z + Wr[gg][0].w * h0.w +
                            Wr[gg][1].x * h1.x + Wr[gg][1].y * h1.y + Wr[gg][1].z * h1.z + Wr[gg][1].w * h1.w +
                            Wr[gg][2].x * h2.x + Wr[gg][2].y * h2.y + Wr[gg][2].z * h2.z + Wr[gg][2].w * h2.w +
                            Wr[gg][3].x * h3.x + Wr[gg][3].y * h3.y + Wr[gg][3].z * h3.z + Wr[gg][3].w * h3.w;
                    }
                }
                // reduce-scatter 16 values over lane bits 1,2,4,8; hi keeps
                // top half (lane-bit == value-bit after each step).
                {   // step 1: mask 1 (DPP, VALU pipe), 8 sends  (v3 = i2)
                    const bool hi = (l & 1) != 0;
#pragma unroll
                    for (int x = 0; x < 8; ++x) {
                        float a = P[x], b2 = P[8 + x];
                        float keep = hi ? b2 : a;
                        float send = hi ? a : b2;
                        P[x] = keep + DPP_XOR1(send);
                    }
                }
                {   // step 2: mask 2 (DPP), 4 sends            (v2 = i1)
                    const bool hi = (l & 2) != 0;
#pragma unroll
                    for (int x = 0; x < 4; ++x) {
                        float a = P[x], b2 = P[4 + x];
                        float keep = hi ? b2 : a;
                        float send = hi ? a : b2;
                        P[x] = keep + DPP_XOR2(send);
                    }
                }
                {   // step 3: mask 4, 2 sends                  (v1 = i0)
                    const bool hi = (l & 4) != 0;
#pragma unroll
                    for (int x = 0; x < 2; ++x) {
                        float a = P[x], b2 = P[2 + x];
                        float keep = hi ? b2 : a;
                        float send = hi ? a : b2;
                        P[x] = keep + __shfl_xor(send, 4, 64);
                    }
                }
                {   // step 4: mask 8, 1 send                   (v0 = gg)
                    const bool hi = (l & 8) != 0;
                    float a = P[0], b2 = P[1];
                    float keep = hi ? b2 : a;
                    float send = hi ? a : b2;
                    P[0] = keep + __shfl_xor(send, 8, 64);
                }
                // step 5: mask 16 allreduce (bit4 not a value bit -> dup)
                P[0] += __shfl_xor(P[0], 16, 64);

                if      (gb == 0) Xv0 = P[0];
                else if (gb == 1) Xv1 = P[0];
                else if (gb == 2) Xv2 = P[0];
                else if (gb == 3) Xv3 = P[0];
                else if (gb == 4) Xv4 = P[0];
                else if (gb == 5) Xv5 = P[0];
                else if (gb == 6) Xv6 = P[0];
                else              Xv7 = P[0];
            }
        }
        // Two 4x4 lane transposes across bits {5 (rh), 3 (gg_p)}: trade gate
        // bits for b-group bits. Pass A: gb 0-3 -> task (bp, jp); pass B:
        // gb 4-7 -> task (bp+32, jp). Then pointwise for both tasks.
        const bool qb = rh != 0, pb = gg_p != 0;
#pragma unroll
        for (int pass = 0; pass < 2; ++pass) {
            float V0 = pass ? Xv4 : Xv0, V1 = pass ? Xv5 : Xv1;
            float V2 = pass ? Xv6 : Xv2, V3 = pass ? Xv7 : Xv3;
            float rA = __shfl_xor(qb ? V0 : V2, 32, 64);
            float rB = __shfl_xor(qb ? V1 : V3, 32, 64);
            float U0 = qb ? rA : V0, U1 = qb ? rB : V1;
            float U2 = qb ? V2 : rA, U3 = qb ? V3 : rB;
            float sA = __shfl_xor(pb ? U0 : U1, 8, 64);
            float sB = __shfl_xor(pb ? U2 : U3, 8, 64);
            float Y0 = pb ? sA : U0, Y1 = pb ? U1 : sA;
            float Y2 = pb ? sB : U2, Y3 = pb ? U3 : sB;

            float4 gv = pass ? gvB : gvA;
            float cr = pass ? cr1 : cr0;

            float gi = Y0 + gv.x;
            float gf = Y1 + gv.y;
            float gc = Y2 + gv.z;
            float go = Y3 + gv.w;

            float si = 1.f / (1.f + __expf(-gi));
            float sf = 1.f / (1.f + __expf(-gf));
            float so = 1.f / (1.f + __expf(-go));
            float tg = 1.f - 2.f / (1.f + __expf(2.f * gc));
            float cv = sf * cr + si * tg;
            if (pass) cr1 = cv; else cr0 = cv;
            float th = 1.f - 2.f / (1.f + __expf(2.f * cv));
            float hv = so * th;

            const int bpp = bp + (pass ? 32 : 0);
            // dup lanes split the two stores (identical values either way)
            if (dup == 0) {
                float* hw = (t & 1) ? hB : hA;
                hw[hpos + (pass ? (size_t)32 * HID : 0)] = hv;    // exchange buf
            } else {
                hiddens[((size_t)bpp * Tt + t) * HID + jp] = hv;  // for GEMM 7
            }
        }
        __syncthreads();   // all waves drain reads+stores (vmcnt0 at barrier)
        if (tid == 0) {
            __threadfence();
            __hip_atomic_fetch_add(&flags[bt], 1u, __ATOMIC_RELEASE,
                                   __HIP_MEMORY_SCOPE_AGENT);
        }
    }
}

extern "C" void kernel_launch(void* const* d_in, const int* in_sizes, int n_in,
                              void* d_out, int out_size, void* d_ws, size_t ws_size,
                              hipStream_t stream)
{
    const float* images = (const float*)d_in[0];
    const float* caps   = (const float*)d_in[1];
    const float* W_fc   = (const float*)d_in[2];
    const float* b_fc   = (const float*)d_in[3];
    const float* W_att  = (const float*)d_in[4];
    const float* b_att  = (const float*)d_in[5];
    const float* W_ih   = (const float*)d_in[6];
    const float* b_ih   = (const float*)d_in[7];
    const float* W_hh   = (const float*)d_in[8];
    const float* b_hh   = (const float*)d_in[9];
    const float* W_out  = (const float*)d_in[10];
    const float* b_out  = (const float*)d_in[11];
    float* out = (float*)d_out;

    float* ws       = (float*)d_ws;
    float* feats    = ws;                  // 256*256
    float* att_base = feats + 65536;       // 256*256
    float* gin_base = att_base + 65536;    // 256*2048 (gate-interleaved)
    float* hA       = gin_base + 524288;   // 256*512 (transposed layout)
    float* hB       = hA + 131072;
    float* ctx_all  = hB + 131072;         // 32768*256
    float* hiddens  = ctx_all + 8388608;   // 32768*512
    float* gin_all  = hiddens + 16777216;  // 32768*2048 (gate-interleaved)
    unsigned int* flags = (unsigned int*)(gin_all + 67108864);  // 8 counters

    hipMemsetAsync(flags, 0, 8 * sizeof(unsigned int), stream);

    // 1. feats = images @ W_fc^T + b_fc            [256,256]
    gemm_bt<<<dim3(4, 4), 256, 0, stream>>>(images, W_fc, b_fc, nullptr, feats,
        256, 256, 2048, 2048, 2048, 256, 0, 1, 0);
    // 2. att_base = feats @ W_att[:, :256]^T + b_att   [256,256]
    gemm_bt<<<dim3(4, 4), 256, 0, stream>>>(feats, W_att, b_att, nullptr, att_base,
        256, 256, 256, 256, 768, 256, 0, 1, 0);
    // 3. gin_base = feats @ W_ih[:, :256]^T + b_ih     [256,2048] gate-interleaved
    gemm_bt<<<dim3(32, 4), 256, 0, stream>>>(feats, W_ih, b_ih, nullptr, gin_base,
        256, 2048, 256, 256, 512, 2048, 0, 1, 1);
    // 4. ctx_all = caps @ W_att[:, 256:]^T + att_base  [32768,256]
    gemm_bt<<<dim3(4, 512), 256, 0, stream>>>(caps, W_att + 256, nullptr, att_base, ctx_all,
        32768, 256, 512, 512, 768, 256, 256, Tt, 0);
    // 5. gin_all = ctx_all @ W_ih[:, 256:]^T + gin_base + b_hh   [32768,2048] interleaved
    gemm_bt<<<dim3(32, 512), 256, 0, stream>>>(ctx_all, W_ih + 256, b_hh, gin_base, gin_all,
        32768, 2048, 256, 256, 512, 2048, 2048, Tt, 1);

    // 6. recurrence: weight-stationary persistent kernel, 256 x 512, flag-synced
    {
        void* args[] = { (void*)&gin_all, (void*)&W_hh, (void*)&hA, (void*)&hB,
                         (void*)&hiddens, (void*)&flags };
        hipLaunchCooperativeKernel((void*)lstm_seq, dim3(256), dim3(512),
                                   args, 0, stream);
    }

    // 7. out = hiddens @ W_out^T + b_out   [32768,1004]
    gemm_bt<<<dim3(16, 512), 256, 0, stream>>>(hiddens, W_out, b_out, nullptr, out,
        32768, 1004, 512, 512, 512, 1004, 0, 1, 0);
}

// Round 11
// 5661.928 us; speedup vs baseline: 2.1048x; 1.2376x over previous
//
#include <hip/hip_runtime.h>

#define Tt  128
#define HID 512

// DPP quad-perm helper: cross-lane xor-1 / xor-2 on the VALU pipe (no DS op).
#define DPP_QP(x, CTRL) \
    __int_as_float(__builtin_amdgcn_update_dpp( \
        __float_as_int(x), __float_as_int(x), (CTRL), 0xF, 0xF, false))
#define DPP_XOR1(x) DPP_QP(x, 0xB1)   // quad_perm [1,0,3,2]
#define DPP_XOR2(x) DPP_QP(x, 0x4E)   // quad_perm [2,3,0,1]

// Generic C[m,n] = sum_k A[m,k]*Bw[r(n),k] (+bias[r(n)]) (+C0[m/c0div, n])
// nperm: physical col n <-> logical weight row r(n) = (n&3)*512 + (n>>2),
// i.e. output stored gate-interleaved [.., j, 4gates] while writes stay coalesced.
__global__ __launch_bounds__(256)
void gemm_bt(const float* __restrict__ A, const float* __restrict__ Bw,
             const float* __restrict__ bias, const float* __restrict__ C0,
             float* __restrict__ C,
             int M, int N, int K, int lda, int ldb, int ldc, int ldc0,
             int c0div, int nperm)
{
    __shared__ float As[16][68];
    __shared__ float Bs[16][68];
    const int n0 = blockIdx.x * 64;
    const int m0 = blockIdx.y * 64;
    const int tid = threadIdx.x;
    const int tx = tid & 15, ty = tid >> 4;
    float acc[4][4];
#pragma unroll
    for (int i = 0; i < 4; i++)
#pragma unroll
        for (int j = 0; j < 4; j++) acc[i][j] = 0.f;

    for (int k0 = 0; k0 < K; k0 += 16) {
#pragma unroll
        for (int i = 0; i < 4; i++) {
            int e = tid + i * 256;
            int m = e >> 4, k = e & 15;
            As[k][m] = A[(size_t)(m0 + m) * lda + (k0 + k)];
        }
#pragma unroll
        for (int i = 0; i < 4; i++) {
            int e = tid + i * 256;
            int n = e >> 4, k = e & 15;
            int gn = n0 + n;
            int gr = nperm ? ((gn & 3) * HID + (gn >> 2)) : gn;
            Bs[k][n] = (gn < N) ? Bw[(size_t)gr * ldb + (k0 + k)] : 0.f;
        }
        __syncthreads();
#pragma unroll
        for (int kk = 0; kk < 16; kk++) {
            float4 av = *(const float4*)&As[kk][ty * 4];
            float4 bv = *(const float4*)&Bs[kk][tx * 4];
            float a[4] = {av.x, av.y, av.z, av.w};
            float b[4] = {bv.x, bv.y, bv.z, bv.w};
#pragma unroll
            for (int i = 0; i < 4; i++)
#pragma unroll
                for (int j = 0; j < 4; j++)
                    acc[i][j] += a[i] * b[j];
        }
        __syncthreads();
    }
#pragma unroll
    for (int i = 0; i < 4; i++) {
        int m = m0 + ty * 4 + i;
        const float* c0row = C0 ? (C0 + (size_t)(m / c0div) * ldc0) : nullptr;
#pragma unroll
        for (int j = 0; j < 4; j++) {
            int n = n0 + tx * 4 + j;
            if (n < N) {
                float v = acc[i][j];
                if (bias)  v += bias[nperm ? ((n & 3) * HID + (n >> 2)) : n];
                if (c0row) v += c0row[n];
                C[(size_t)m * ldc + n] = v;
            }
        }
    }
}

// Weight-stationary persistent LSTM recurrence (r10 algorithm, verified) with
// the SYNC MECHANISM fixed. r0-r10 evidence: per-step time is ~36-45 us
// regardless of compute volume (even 6.7 GB of spill traffic was nearly
// free) -> the recurrence is bound by the per-step inter-block sync chain,
// not compute/DS/BW. Suspected mechanism: (a) the tid0 spin used ACQUIRE
// loads -> every poll emits cache-invalidate ops, an invalidation storm from
// up to 64 waiting CUs per pipeline; (b) release did __threadfence() AND a
// RELEASE fetch_add -> two L2-writeback-class ops on the critical path.
// Fix: RELAXED polling + ONE acquire load after detection; release via the
// RELEASE fetch_add alone (it already orders prior stores per the model).
//
// Geometry (proven r10): 256 blocks x 512 threads, 1 block/CU (128 KB LDS),
// 128-VGPR cap respected (~100 live). bt = blockIdx&3 -> 4 pipelines of 64
// blocks, 64 b rows each. jt = blockIdx>>2 in [0,64): 8 j x 4 gates = 32 W
// rows/block; wave w owns j = j0+w. Lane: bit5 = rh (gate pair), bits0-4 =
// kc (16-float k chunk), bit4 = dup bit. Thread W slice: 2 rows x 16 k = 32
// VGPR. Per step: MAC over 64 b in 8 groups of 8 (P[16]), 4-step RS over
// lane bits 1,2,4,8 (masks 1,2 on DPP/VALU) + mask-16 allreduce (dup), two
// 4x4 lane transposes across bits {32, 8} -> each lane owns 2 (b,j) tasks;
// dup lanes split the exchange-buf / hiddens stores.
__global__ __launch_bounds__(512)
void lstm_seq(const float* __restrict__ gin, const float* __restrict__ Whh,
              float* __restrict__ hA, float* __restrict__ hB,
              float* __restrict__ hiddens, unsigned int* __restrict__ flags)
{
    __shared__ float4 Hs[8192];        // 128 KB: [b_local 0..63][kk4 0..3][kc 0..31]
    const int tid = threadIdx.x;
    const int l   = tid & 63;
    const int w   = tid >> 6;          // 0..7 -> j (wave index)
    const int bt  = blockIdx.x & 3;
    const int jt  = blockIdx.x >> 2;   // 0..63
    const int b0  = bt * 64;
    const int j0  = jt * 8;
    const int rh  = l >> 5;            // gate-pair bit
    const int kc  = l & 31;            // k chunk [kc*16, kc*16+16)

    // one-time W_hh load: 2 rows x 4 float4 = 32 VGPR. gate = rh*2+gg, col j0+w
    float4 Wr[2][4];
#pragma unroll
    for (int gg = 0; gg < 2; ++gg) {
        const float4* src = (const float4*)Whh +
            (size_t)((rh * 2 + gg) * HID + j0 + w) * 128 + kc * 4;
#pragma unroll
        for (int q2 = 0; q2 < 4; ++q2) Wr[gg][q2] = src[q2];
    }

    // pointwise task decode (RS consumes: mask1<->i2, mask2<->i1, mask4<->i0,
    // mask8<->gg; mask16 = allreduce -> bit4 is a pure duplicate)
    const int i_p  = ((kc & 1) << 2) | (kc & 2) | ((kc >> 2) & 1);
    const int gg_p = (kc >> 3) & 1;
    const int dup  = (kc >> 4) & 1;
    const int bp = b0 + (rh * 2 + gg_p) * 8 + i_p;   // task 1 b (task 2 = bp+32)
    const int jp = j0 + w;                           // global j
    // transposed h position (float index) for (bp, jp): k == jp
    const size_t hpos = ((size_t)bp * 128 + ((jp >> 2) & 3) * 32 + (jp >> 4)) * 4 + (jp & 3);

    float cr0 = 0.f, cr1 = 0.f;

    for (int t = 0; t < Tt; ++t) {
        // prefetch the 4 gate inputs for both tasks (gin is [b][t][j][4])
        float4 gvA = *(const float4*)(gin + ((size_t)bp * Tt + t) * 2048 + jp * 4);
        float4 gvB = *(const float4*)(gin + ((size_t)(bp + 32) * Tt + t) * 2048 + jp * 4);

        float Xv0 = 0.f, Xv1 = 0.f, Xv2 = 0.f, Xv3 = 0.f;
        float Xv4 = 0.f, Xv5 = 0.f, Xv6 = 0.f, Xv7 = 0.f;
        if (t > 0) {
            if (tid == 0) {
                const unsigned tgt = 64u * (unsigned)t;
                // RELAXED spin: no per-poll cache invalidation
                unsigned v;
                do {
                    v = __hip_atomic_load(&flags[bt], __ATOMIC_RELAXED,
                                          __HIP_MEMORY_SCOPE_AGENT);
                    if (v < tgt) __builtin_amdgcn_s_sleep(1);
                } while (v < tgt);
                // single ACQUIRE to publish producers' stores to this CU
                // (value used so the load cannot be elided; counter is
                // monotonic so the branch never fires)
                if (__hip_atomic_load(&flags[bt], __ATOMIC_ACQUIRE,
                                      __HIP_MEMORY_SCOPE_AGENT) < tgt)
                    __builtin_amdgcn_s_sleep(1);
            }
            __syncthreads();
            // stage 64 b x 512 h (128 KB) -> LDS in two 8-float4 rounds
            {
                const float4* hin4 =
                    (const float4*)(((t - 1) & 1) ? hB : hA) + (size_t)b0 * 128;
                float4 tmp[8];
#pragma unroll
                for (int q2 = 0; q2 < 8; ++q2)
                    tmp[q2] = hin4[(q2 * 8 + w) * 64 + l];
#pragma unroll
                for (int q2 = 0; q2 < 8; ++q2)
                    Hs[(q2 * 8 + w) * 64 + l] = tmp[q2];
#pragma unroll
                for (int q2 = 0; q2 < 8; ++q2)
                    tmp[q2] = hin4[((q2 + 8) * 8 + w) * 64 + l];
#pragma unroll
                for (int q2 = 0; q2 < 8; ++q2)
                    Hs[((q2 + 8) * 8 + w) * 64 + l] = tmp[q2];
            }
            __syncthreads();

#pragma unroll
            for (int gb = 0; gb < 8; ++gb) {       // 8 b-groups of 8
                float P[16];                       // [i 0..7][gg 0..1]
#pragma unroll
                for (int v = 0; v < 16; ++v) P[v] = 0.f;
#pragma unroll
                for (int i = 0; i < 8; ++i) {
                    const float4* hp = &Hs[(gb * 8 + i) * 128 + kc];
                    float4 h0 = hp[0], h1 = hp[32], h2 = hp[64], h3 = hp[96];
#pragma unroll
                    for (int gg = 0; gg < 2; ++gg) {
                        P[i * 2 + gg] +=
                            Wr[gg][0].x * h0.x + Wr[gg][0].y * h0.y + Wr[gg][0].z * h0.z + Wr[gg][0].w * h0.w +
                            Wr[gg][1].x * h1.x + Wr[gg][1].y * h1.y + Wr[gg][1].z * h1.z + Wr[gg][1].w * h1.w +
                            Wr[gg][2].x * h2.x + Wr[gg][2].y * h2.y + Wr[gg][2].z * h2.z + Wr[gg][2].w * h2.w +
                            Wr[gg][3].x * h3.x + Wr[gg][3].y * h3.y + Wr[gg][3].z * h3.z + Wr[gg][3].w * h3.w;
                    }
                }
                // reduce-scatter 16 values over lane bits 1,2,4,8; hi keeps
                // top half (lane-bit == value-bit after each step).
                {   // step 1: mask 1 (DPP, VALU pipe), 8 sends  (v3 = i2)
                    const bool hi = (l & 1) != 0;
#pragma unroll
                    for (int x = 0; x < 8; ++x) {
                        float a = P[x], b2 = P[8 + x];
                        float keep = hi ? b2 : a;
                        float send = hi ? a : b2;
                        P[x] = keep + DPP_XOR1(send);
                    }
                }
                {   // step 2: mask 2 (DPP), 4 sends            (v2 = i1)
                    const bool hi = (l & 2) != 0;
#pragma unroll
                    for (int x = 0; x < 4; ++x) {
                        float a = P[x], b2 = P[4 + x];
                        float keep = hi ? b2 : a;
                        float send = hi ? a : b2;
                        P[x] = keep + DPP_XOR2(send);
                    }
                }
                {   // step 3: mask 4, 2 sends                  (v1 = i0)
                    const bool hi = (l & 4) != 0;
#pragma unroll
                    for (int x = 0; x < 2; ++x) {
                        float a = P[x], b2 = P[2 + x];
                        float keep = hi ? b2 : a;
                        float send = hi ? a : b2;
                        P[x] = keep + __shfl_xor(send, 4, 64);
                    }
                }
                {   // step 4: mask 8, 1 send                   (v0 = gg)
                    const bool hi = (l & 8) != 0;
                    float a = P[0], b2 = P[1];
                    float keep = hi ? b2 : a;
                    float send = hi ? a : b2;
                    P[0] = keep + __shfl_xor(send, 8, 64);
                }
                // step 5: mask 16 allreduce (bit4 not a value bit -> dup)
                P[0] += __shfl_xor(P[0], 16, 64);

                if      (gb == 0) Xv0 = P[0];
                else if (gb == 1) Xv1 = P[0];
                else if (gb == 2) Xv2 = P[0];
                else if (gb == 3) Xv3 = P[0];
                else if (gb == 4) Xv4 = P[0];
                else if (gb == 5) Xv5 = P[0];
                else if (gb == 6) Xv6 = P[0];
                else              Xv7 = P[0];
            }
        }
        // Two 4x4 lane transposes across bits {5 (rh), 3 (gg_p)}: trade gate
        // bits for b-group bits. Pass A: gb 0-3 -> task (bp, jp); pass B:
        // gb 4-7 -> task (bp+32, jp). Then pointwise for both tasks.
        const bool qb = rh != 0, pb = gg_p != 0;
#pragma unroll
        for (int pass = 0; pass < 2; ++pass) {
            float V0 = pass ? Xv4 : Xv0, V1 = pass ? Xv5 : Xv1;
            float V2 = pass ? Xv6 : Xv2, V3 = pass ? Xv7 : Xv3;
            float rA = __shfl_xor(qb ? V0 : V2, 32, 64);
            float rB = __shfl_xor(qb ? V1 : V3, 32, 64);
            float U0 = qb ? rA : V0, U1 = qb ? rB : V1;
            float U2 = qb ? V2 : rA, U3 = qb ? V3 : rB;
            float sA = __shfl_xor(pb ? U0 : U1, 8, 64);
            float sB = __shfl_xor(pb ? U2 : U3, 8, 64);
            float Y0 = pb ? sA : U0, Y1 = pb ? U1 : sA;
            float Y2 = pb ? sB : U2, Y3 = pb ? U3 : sB;

            float4 gv = pass ? gvB : gvA;
            float cr = pass ? cr1 : cr0;

            float gi = Y0 + gv.x;
            float gf = Y1 + gv.y;
            float gc = Y2 + gv.z;
            float go = Y3 + gv.w;

            float si = 1.f / (1.f + __expf(-gi));
            float sf = 1.f / (1.f + __expf(-gf));
            float so = 1.f / (1.f + __expf(-go));
            float tg = 1.f - 2.f / (1.f + __expf(2.f * gc));
            float cv = sf * cr + si * tg;
            if (pass) cr1 = cv; else cr0 = cv;
            float th = 1.f - 2.f / (1.f + __expf(2.f * cv));
            float hv = so * th;

            const int bpp = bp + (pass ? 32 : 0);
            // dup lanes split the two stores (identical values either way)
            if (dup == 0) {
                float* hw = (t & 1) ? hB : hA;
                hw[hpos + (pass ? (size_t)32 * HID : 0)] = hv;    // exchange buf
            } else {
                hiddens[((size_t)bpp * Tt + t) * HID + jp] = hv;  // for GEMM 7
            }
        }
        __syncthreads();   // all waves drain reads+stores (vmcnt0 at barrier)
        if (tid == 0) {
            // RELEASE add alone: orders + publishes all prior stores
            // (the old extra __threadfence() doubled the L2-writeback cost)
            __hip_atomic_fetch_add(&flags[bt], 1u, __ATOMIC_RELEASE,
                                   __HIP_MEMORY_SCOPE_AGENT);
        }
    }
}

extern "C" void kernel_launch(void* const* d_in, const int* in_sizes, int n_in,
                              void* d_out, int out_size, void* d_ws, size_t ws_size,
                              hipStream_t stream)
{
    const float* images = (const float*)d_in[0];
    const float* caps   = (const float*)d_in[1];
    const float* W_fc   = (const float*)d_in[2];
    const float* b_fc   = (const float*)d_in[3];
    const float* W_att  = (const float*)d_in[4];
    const float* b_att  = (const float*)d_in[5];
    const float* W_ih   = (const float*)d_in[6];
    const float* b_ih   = (const float*)d_in[7];
    const float* W_hh   = (const float*)d_in[8];
    const float* b_hh   = (const float*)d_in[9];
    const float* W_out  = (const float*)d_in[10];
    const float* b_out  = (const float*)d_in[11];
    float* out = (float*)d_out;

    float* ws       = (float*)d_ws;
    float* feats    = ws;                  // 256*256
    float* att_base = feats + 65536;       // 256*256
    float* gin_base = att_base + 65536;    // 256*2048 (gate-interleaved)
    float* hA       = gin_base + 524288;   // 256*512 (transposed layout)
    float* hB       = hA + 131072;
    float* ctx_all  = hB + 131072;         // 32768*256
    float* hiddens  = ctx_all + 8388608;   // 32768*512
    float* gin_all  = hiddens + 16777216;  // 32768*2048 (gate-interleaved)
    unsigned int* flags = (unsigned int*)(gin_all + 67108864);  // 8 counters

    hipMemsetAsync(flags, 0, 8 * sizeof(unsigned int), stream);

    // 1. feats = images @ W_fc^T + b_fc            [256,256]
    gemm_bt<<<dim3(4, 4), 256, 0, stream>>>(images, W_fc, b_fc, nullptr, feats,
        256, 256, 2048, 2048, 2048, 256, 0, 1, 0);
    // 2. att_base = feats @ W_att[:, :256]^T + b_att   [256,256]
    gemm_bt<<<dim3(4, 4), 256, 0, stream>>>(feats, W_att, b_att, nullptr, att_base,
        256, 256, 256, 256, 768, 256, 0, 1, 0);
    // 3. gin_base = feats @ W_ih[:, :256]^T + b_ih     [256,2048] gate-interleaved
    gemm_bt<<<dim3(32, 4), 256, 0, stream>>>(feats, W_ih, b_ih, nullptr, gin_base,
        256, 2048, 256, 256, 512, 2048, 0, 1, 1);
    // 4. ctx_all = caps @ W_att[:, 256:]^T + att_base  [32768,256]
    gemm_bt<<<dim3(4, 512), 256, 0, stream>>>(caps, W_att + 256, nullptr, att_base, ctx_all,
        32768, 256, 512, 512, 768, 256, 256, Tt, 0);
    // 5. gin_all = ctx_all @ W_ih[:, 256:]^T + gin_base + b_hh   [32768,2048] interleaved
    gemm_bt<<<dim3(32, 512), 256, 0, stream>>>(ctx_all, W_ih + 256, b_hh, gin_base, gin_all,
        32768, 2048, 256, 256, 512, 2048, 2048, Tt, 1);

    // 6. recurrence: weight-stationary persistent kernel, 256 x 512, flag-synced
    {
        void* args[] = { (void*)&gin_all, (void*)&W_hh, (void*)&hA, (void*)&hB,
                         (void*)&hiddens, (void*)&flags };
        hipLaunchCooperativeKernel((void*)lstm_seq, dim3(256), dim3(512),
                                   args, 0, stream);
    }

    // 7. out = hiddens @ W_out^T + b_out   [32768,1004]
    gemm_bt<<<dim3(16, 512), 256, 0, stream>>>(hiddens, W_out, b_out, nullptr, out,
        32768, 1004, 512, 512, 512, 1004, 0, 1, 0);
}